// Round 6
// baseline (6078.400 us; speedup 1.0000x reference)
//
#include <hip/hip_runtime.h>

#define H 51
#define T_LEN 8192
#define CHUNK 64
#define ROWP 53   // LDS row stride (floats): odd stride -> conflict-free rows

__device__ __forceinline__ float fast_sigmoid(float x) {
    float e = __builtin_amdgcn_exp2f(x * -1.44269504088896341f);
    return __builtin_amdgcn_rcpf(1.0f + e);
}

__device__ __forceinline__ float fast_tanh(float x) {
    // tanh(x) = 2/(1+exp(-2x)) - 1 ; rcp(inf)=0 handles saturation.
    float e = __builtin_amdgcn_exp2f(x * -2.88539008177792681f);
    float r = __builtin_amdgcn_rcpf(1.0f + e);
    return fmaf(2.0f, r, -1.0f);
}

__device__ __forceinline__ float bcast_lane(float v, int lane) {
    return __int_as_float(__builtin_amdgcn_readlane(__float_as_int(v), lane));
}

// One wave (64 lanes) per batch element. Lane L owns hidden unit L (lanes
// 51..63 hold zeroed weights/biases -> gates 0 -> i=f=o=0.5, g=0 ->
// c'=0.5*c=0, h'=0). h-broadcast is pure v_readlane; no barriers in the
// step loop. Output projection deferred to chunk end via LDS h-history.
extern "C" __global__ void
__launch_bounds__(64)
__attribute__((amdgpu_waves_per_eu(1, 1)))
lstm_fused(const float* __restrict__ input,   // [B, T]
           const float* __restrict__ W_ih,    // [204, 1]
           const float* __restrict__ W_hh,    // [204, 51]
           const float* __restrict__ b_ih,    // [204]
           const float* __restrict__ b_hh,    // [204]
           const float* __restrict__ W_lin,   // [2, 51]
           const float* __restrict__ b_lin,   // [2]
           float* __restrict__ out)           // [B, 2, T]
{
    const int L = threadIdx.x;
    const int b = blockIdx.x;
    const bool act = (L < H);

    __shared__ __align__(16) float sh[CHUNK * ROWP];   // h history for 64 steps

    // ---- one-time weight load into registers (4 rows of 51 per lane) ----
    float w[4][H];
#pragma unroll
    for (int g = 0; g < 4; ++g) {
#pragma unroll
        for (int k = 0; k < H; ++k) {
            w[g][k] = act ? W_hh[(g * H + L) * H + k] : 0.0f;
        }
    }
    float wi[4], bsum[4];
#pragma unroll
    for (int g = 0; g < 4; ++g) {
        wi[g]   = act ? W_ih[g * H + L] : 0.0f;
        bsum[g] = act ? (b_ih[g * H + L] + b_hh[g * H + L]) : 0.0f;
    }
    // Pin weights as opaque register values: blocks rematerialization and
    // AGPR-parking (R4: VGPR_Count=124 with ~710 VALU instr/step ->
    // v_accvgpr_read per FMA operand). 204 + ~30 working fits at 1 wave/EU.
#pragma unroll
    for (int g = 0; g < 4; ++g) {
#pragma unroll
        for (int k = 0; k < H; ++k) {
            asm volatile("" : "+v"(w[g][k]));
        }
        asm volatile("" : "+v"(wi[g]), "+v"(bsum[g]));
    }

    const float bl0 = b_lin[0];
    const float bl1 = b_lin[1];

    float h = 0.0f, c = 0.0f;

    const float* inrow = input + (size_t)b * T_LEN;
    float* out0 = out + (size_t)b * 2 * T_LEN;
    float* out1 = out0 + T_LEN;

    // input prefetch: chunk n+1 loads while chunk n computes (64 steps cover)
    float x_cur = inrow[L];

    for (int t0 = 0; t0 < T_LEN; t0 += CHUNK) {
        float x_next = 0.0f;
        if (t0 + CHUNK < T_LEN) x_next = inrow[t0 + CHUNK + L];

        for (int k = 0; k < CHUNK; ++k) {
            const float xk = bcast_lane(x_cur, k);

            float acc0 = fmaf(xk, wi[0], bsum[0]);
            float acc1 = fmaf(xk, wi[1], bsum[1]);
            float acc2 = fmaf(xk, wi[2], bsum[2]);
            float acc3 = fmaf(xk, wi[3], bsum[3]);
            // matvec: broadcast h[kk] via v_readlane (SGPR operand), FMA vs
            // per-lane weight VGPRs. 51 readlanes + 204 FMAs, no memory ops.
#pragma unroll
            for (int kk = 0; kk < H; ++kk) {
                const float hk = bcast_lane(h, kk);
                acc0 = fmaf(hk, w[0][kk], acc0);
                acc1 = fmaf(hk, w[1][kk], acc1);
                acc2 = fmaf(hk, w[2][kk], acc2);
                acc3 = fmaf(hk, w[3][kk], acc3);
            }

            const float ig = fast_sigmoid(acc0);
            const float fg = fast_sigmoid(acc1);
            const float gg = fast_tanh(acc2);
            const float og = fast_sigmoid(acc3);
            c = fmaf(fg, c, ig * gg);
            h = og * fast_tanh(c);

            // defer output projection: 1 conflict-free ds_write per step
            sh[k * ROWP + L] = h;
        }

        __syncthreads();   // wave-sized block: compiles to a waitcnt fence

        // chunk-end projection: lane L handles step t0+L. Row stride 53
        // floats -> banks (53L+kk)%32 distinct across lanes -> conflict-free.
        // W_lin is lane-uniform -> scalar loads, amortized over 64 steps.
        float o0 = bl0, o1 = bl1;
        const float* hr = &sh[L * ROWP];
#pragma unroll
        for (int kk = 0; kk < H; ++kk) {
            const float hk = hr[kk];
            o0 = fmaf(hk, W_lin[kk],     o0);
            o1 = fmaf(hk, W_lin[H + kk], o1);
        }
        out0[t0 + L] = o0;            // coalesced, 64 steps at once
        out1[t0 + L] = o1;

        __syncthreads();   // reads done before next chunk's ds_writes
        x_cur = x_next;
    }
}

extern "C" void kernel_launch(void* const* d_in, const int* in_sizes, int n_in,
                              void* d_out, int out_size, void* d_ws, size_t ws_size,
                              hipStream_t stream) {
    const float* input = (const float*)d_in[0];
    const float* W_ih  = (const float*)d_in[1];
    const float* W_hh  = (const float*)d_in[2];
    const float* b_ih  = (const float*)d_in[3];
    const float* b_hh  = (const float*)d_in[4];
    const float* W_lin = (const float*)d_in[5];
    const float* b_lin = (const float*)d_in[6];
    float* outp = (float*)d_out;

    const int B = in_sizes[0] / T_LEN;   // 1024
    lstm_fused<<<dim3(B), dim3(64), 0, stream>>>(
        input, W_ih, W_hh, b_ih, b_hh, W_lin, b_lin, outp);
}

// Round 13
// 3975.089 us; speedup vs baseline: 1.5291x; 1.5291x over previous
//
#include <hip/hip_runtime.h>

#define H 51
#define T_LEN 8192
#define CHUNK 64
#define ROWP 53    // LDS row stride (floats): 53%32=21, gcd(21,32)=1 -> 2 lanes/bank (free)
#define NPAIR 26   // 26 f16x2 pairs cover 51 (+1 zero pad)

__device__ __forceinline__ float fast_sigmoid(float x) {
    float e = __builtin_amdgcn_exp2f(x * -1.44269504088896341f);
    return __builtin_amdgcn_rcpf(1.0f + e);
}

__device__ __forceinline__ float fast_tanh(float x) {
    // tanh(x) = 2/(1+exp(-2x)) - 1 ; rcp(inf)=0 handles saturation.
    float e = __builtin_amdgcn_exp2f(x * -2.88539008177792681f);
    float r = __builtin_amdgcn_rcpf(1.0f + e);
    return fmaf(2.0f, r, -1.0f);
}

// Pack two floats as f16x2 bits with RNE (v_cvt_f16_f32 is RNE). Unbiased,
// unlike v_cvt_pkrtz_f16_f32 (RTZ) whose bias accumulates through the
// 8192-step recurrence (R11 failed absmax by 2.6% with RTZ).
__device__ __forceinline__ int pack_f16_rne(float a, float b) {
    unsigned short lo = __builtin_bit_cast(unsigned short, (_Float16)a);
    unsigned short hi = __builtin_bit_cast(unsigned short, (_Float16)b);
    return (int)lo | ((int)hi << 16);
}

// acc += w.x*h.x + w.y*h.y, fp32 accumulate. Raw 32-bit regs only.
__device__ __forceinline__ float dot2f(float acc, int wbits, int hbits) {
    asm("v_dot2_f32_f16 %0, %1, %2, %0" : "+v"(acc) : "v"(wbits), "v"(hbits));
    return acc;
}

// One wave (64 lanes) per batch element. Lane L owns hidden unit L (lanes
// 51..63 hold zeroed weights/biases -> gates 0 -> i=f=o=0.5, g=0 ->
// c'=0.5*c=0, h'=0; so h[51]==0 makes lane-50's (h50,h51) pair exact).
// Weights as f16-pair bits; g-gate weights carry an f16 lo-correction
// (hi/lo split) since g's error enters c additively. fp32 accum/state.
extern "C" __global__ void __launch_bounds__(64, 1)
lstm_fused(const float* __restrict__ input,   // [B, T]
           const float* __restrict__ W_ih,    // [204, 1]
           const float* __restrict__ W_hh,    // [204, 51]
           const float* __restrict__ b_ih,    // [204]
           const float* __restrict__ b_hh,    // [204]
           const float* __restrict__ W_lin,   // [2, 51]
           const float* __restrict__ b_lin,   // [2]
           float* __restrict__ out)           // [B, 2, T]
{
    const int L = threadIdx.x;
    const int b = blockIdx.x;
    const bool act = (L < H);

    __shared__ __align__(16) float sh[CHUNK * ROWP];   // h history per chunk

    // ---- weights: 4 rows x 26 f16-pair ints per lane (RNE, converted once);
    // gate 2 (g) also gets a lo-residual pair array ----
    int wp[4][NPAIR];
    int wlo2[NPAIR];
#pragma unroll
    for (int g = 0; g < 4; ++g) {
#pragma unroll
        for (int j = 0; j < NPAIR; ++j) {
            float wa = 0.0f, wb = 0.0f;
            if (act) {
                wa = W_hh[(g * H + L) * H + 2 * j];
                if (2 * j + 1 < H) wb = W_hh[(g * H + L) * H + 2 * j + 1];
            }
            wp[g][j] = pack_f16_rne(wa, wb);
            if (g == 2) {
                const float ra = wa - (float)(_Float16)wa;
                const float rb = wb - (float)(_Float16)wb;
                wlo2[j] = pack_f16_rne(ra, rb);
            }
        }
    }
    float wi[4], bsum[4];
#pragma unroll
    for (int g = 0; g < 4; ++g) {
        wi[g]   = act ? W_ih[g * H + L] : 0.0f;
        bsum[g] = act ? (b_ih[g * H + L] + b_hh[g * H + L]) : 0.0f;
    }
    const float bl0 = b_lin[0];
    const float bl1 = b_lin[1];

    float h = 0.0f, c = 0.0f;

    const float* inrow = input + (size_t)b * T_LEN;
    float* out0 = out + (size_t)b * 2 * T_LEN;
    float* out1 = out0 + T_LEN;

    // input prefetch: chunk n+1 loads while chunk n computes (64 steps cover)
    float x_cur = inrow[L];

    for (int t0 = 0; t0 < T_LEN; t0 += CHUNK) {
        float x_next = 0.0f;
        if (t0 + CHUNK < T_LEN) x_next = inrow[t0 + CHUNK + L];

        for (int k = 0; k < CHUNK; ++k) {
            // ---- build f16x2 broadcast pairs of h (RNE) ----
            // hn = h from lane+1 (DPP 0x101; validated by R11's tiny error).
            // Readlane targets are even lanes 0..50, so the row-boundary
            // lanes 15/31/47 (whose +1 neighbor is zeroed) are never read.
            const int hn = __builtin_amdgcn_update_dpp(
                0, __float_as_int(h), 0x101, 0xF, 0xF, false);
            const int hpb = pack_f16_rne(h, __int_as_float(hn));
            int hs[NPAIR];
#pragma unroll
            for (int j = 0; j < NPAIR; ++j) {
                hs[j] = __builtin_amdgcn_readlane(hpb, 2 * j);
            }

            const float xk = __int_as_float(
                __builtin_amdgcn_readlane(__float_as_int(x_cur), k));
            float acc0 = fmaf(xk, wi[0], bsum[0]);
            float acc1 = fmaf(xk, wi[1], bsum[1]);
            float acc2 = fmaf(xk, wi[2], bsum[2]);
            float acc3 = fmaf(xk, wi[3], bsum[3]);

            // ---- matvec: 130 v_dot2_f32_f16, weights resident in VGPRs ----
#pragma unroll
            for (int j = 0; j < NPAIR; ++j) {
                acc0 = dot2f(acc0, wp[0][j], hs[j]);
                acc1 = dot2f(acc1, wp[1][j], hs[j]);
                acc2 = dot2f(acc2, wp[2][j], hs[j]);
                acc3 = dot2f(acc3, wp[3][j], hs[j]);
                acc2 = dot2f(acc2, wlo2[j], hs[j]);   // g-gate lo correction
            }

            const float ig = fast_sigmoid(acc0);
            const float fg = fast_sigmoid(acc1);
            const float gg = fast_tanh(acc2);
            const float og = fast_sigmoid(acc3);
            c = fmaf(fg, c, ig * gg);
            h = og * fast_tanh(c);

            // defer output projection: 1 conflict-free ds_write per step
            sh[k * ROWP + L] = h;
        }

        __syncthreads();   // wave-sized block: compiles to a waitcnt fence

        // chunk-end projection (fp32): lane L handles step t0+L. Banks
        // (21L+kk)%32 -> exactly 2 lanes/bank (free, m136). W_lin is
        // lane-uniform -> scalar loads, amortized over 64 steps.
        float o0 = bl0, o1 = bl1;
        const float* hr = &sh[L * ROWP];
#pragma unroll
        for (int kk = 0; kk < H; ++kk) {
            const float hk = hr[kk];
            o0 = fmaf(hk, W_lin[kk],     o0);
            o1 = fmaf(hk, W_lin[H + kk], o1);
        }
        out0[t0 + L] = o0;            // coalesced, 64 steps at once
        out1[t0 + L] = o1;

        __syncthreads();   // reads done before next chunk's ds_writes
        x_cur = x_next;
    }
}

extern "C" void kernel_launch(void* const* d_in, const int* in_sizes, int n_in,
                              void* d_out, int out_size, void* d_ws, size_t ws_size,
                              hipStream_t stream) {
    const float* input = (const float*)d_in[0];
    const float* W_ih  = (const float*)d_in[1];
    const float* W_hh  = (const float*)d_in[2];
    const float* b_ih  = (const float*)d_in[3];
    const float* b_hh  = (const float*)d_in[4];
    const float* W_lin = (const float*)d_in[5];
    const float* b_lin = (const float*)d_in[6];
    float* outp = (float*)d_out;

    const int B = in_sizes[0] / T_LEN;   // 1024
    lstm_fused<<<dim3(B), dim3(64), 0, stream>>>(
        input, W_ih, W_hh, b_ih, b_hh, W_lin, b_lin, outp);
}

// Round 15
// 3954.993 us; speedup vs baseline: 1.5369x; 1.0051x over previous
//
#include <hip/hip_runtime.h>

#define H 51
#define T_LEN 8192
#define CHUNK 64
#define ROWP 53    // LDS row stride (floats): 53%32=21, gcd(21,32)=1 -> 2 lanes/bank (free)
#define NPAIR 26   // 26 f16x2 pairs cover 51 (+1 zero pad)

__device__ __forceinline__ float fast_sigmoid(float x) {
    float e = __builtin_amdgcn_exp2f(x * -1.44269504088896341f);
    return __builtin_amdgcn_rcpf(1.0f + e);
}

__device__ __forceinline__ float fast_tanh(float x) {
    // tanh(x) = 2/(1+exp(-2x)) - 1 ; rcp(inf)=0 handles saturation.
    float e = __builtin_amdgcn_exp2f(x * -2.88539008177792681f);
    float r = __builtin_amdgcn_rcpf(1.0f + e);
    return fmaf(2.0f, r, -1.0f);
}

// Pack two floats as f16x2 bits with RNE (v_cvt_f16_f32 is RNE). Unbiased,
// unlike v_cvt_pkrtz_f16_f32 (RTZ) whose bias accumulates through the
// 8192-step recurrence (R11 failed absmax by 2.6% with RTZ).
__device__ __forceinline__ int pack_f16_rne(float a, float b) {
    unsigned short lo = __builtin_bit_cast(unsigned short, (_Float16)a);
    unsigned short hi = __builtin_bit_cast(unsigned short, (_Float16)b);
    return (int)lo | ((int)hi << 16);
}

// acc += w.x*h.x + w.y*h.y, fp32 accumulate. Raw 32-bit regs only.
__device__ __forceinline__ float dot2f(float acc, int wbits, int hbits) {
    asm("v_dot2_f32_f16 %0, %1, %2, %0" : "+v"(acc) : "v"(wbits), "v"(hbits));
    return acc;
}

// One wave (64 lanes) per batch element. Lane L owns hidden unit L (lanes
// 51..63 hold zeroed weights/biases -> gates 0 -> i=f=o=0.5, g=0 ->
// c'=0.5*c=0, h'=0; so h[51]==0 makes lane-50's (h50,h51) pair exact).
// Weights as f16-pair bits; g-gate weights carry an f16 lo-correction.
// KEY CHANGE vs R13: amdgpu_agpr_alloc(0) forbids AGPR allocation, so the
// 130 weight ints must live in arch VGPRs (R4/R13 diagnosed ~130-204
// v_accvgpr_read copies/step from AGPR parking; R8 proved VALU cannot
// source AGPRs directly, so parking is never free). waves_per_eu(1,1)
// lifts occupancy-driven VGPR caps (1 wave/SIMD is by design: B=1024).
extern "C" __global__ void
__launch_bounds__(64)
__attribute__((amdgpu_waves_per_eu(1, 1)))
__attribute__((amdgpu_agpr_alloc(0)))
lstm_fused(const float* __restrict__ input,   // [B, T]
           const float* __restrict__ W_ih,    // [204, 1]
           const float* __restrict__ W_hh,    // [204, 51]
           const float* __restrict__ b_ih,    // [204]
           const float* __restrict__ b_hh,    // [204]
           const float* __restrict__ W_lin,   // [2, 51]
           const float* __restrict__ b_lin,   // [2]
           float* __restrict__ out)           // [B, 2, T]
{
    const int L = threadIdx.x;
    const int b = blockIdx.x;
    const bool act = (L < H);

    __shared__ __align__(16) float sh[CHUNK * ROWP];   // h history per chunk

    // ---- weights: 4 rows x 26 f16-pair ints per lane (RNE, converted once);
    // gate 2 (g) also gets a lo-residual pair array ----
    int wp[4][NPAIR];
    int wlo2[NPAIR];
#pragma unroll
    for (int g = 0; g < 4; ++g) {
#pragma unroll
        for (int j = 0; j < NPAIR; ++j) {
            float wa = 0.0f, wb = 0.0f;
            if (act) {
                wa = W_hh[(g * H + L) * H + 2 * j];
                if (2 * j + 1 < H) wb = W_hh[(g * H + L) * H + 2 * j + 1];
            }
            wp[g][j] = pack_f16_rne(wa, wb);
            if (g == 2) {
                const float ra = wa - (float)(_Float16)wa;
                const float rb = wb - (float)(_Float16)wb;
                wlo2[j] = pack_f16_rne(ra, rb);
            }
        }
    }
    float wi[4], bsum[4];
#pragma unroll
    for (int g = 0; g < 4; ++g) {
        wi[g]   = act ? W_ih[g * H + L] : 0.0f;
        bsum[g] = act ? (b_ih[g * H + L] + b_hh[g * H + L]) : 0.0f;
    }
    const float bl0 = b_lin[0];
    const float bl1 = b_lin[1];

    float h = 0.0f, c = 0.0f;

    const float* inrow = input + (size_t)b * T_LEN;
    float* out0 = out + (size_t)b * 2 * T_LEN;
    float* out1 = out0 + T_LEN;

    // input prefetch: chunk n+1 loads while chunk n computes (64 steps cover)
    float x_cur = inrow[L];

    for (int t0 = 0; t0 < T_LEN; t0 += CHUNK) {
        float x_next = 0.0f;
        if (t0 + CHUNK < T_LEN) x_next = inrow[t0 + CHUNK + L];

        for (int k = 0; k < CHUNK; ++k) {
            // ---- build f16x2 broadcast pairs of h (RNE) ----
            // hn = h from lane+1 (DPP 0x101; validated by R11/R13 accuracy).
            // Readlane targets are even lanes 0..50, so the row-boundary
            // lanes 15/31/47 (whose +1 neighbor is zeroed) are never read.
            const int hn = __builtin_amdgcn_update_dpp(
                0, __float_as_int(h), 0x101, 0xF, 0xF, false);
            const int hpb = pack_f16_rne(h, __int_as_float(hn));
            int hs[NPAIR];
#pragma unroll
            for (int j = 0; j < NPAIR; ++j) {
                hs[j] = __builtin_amdgcn_readlane(hpb, 2 * j);
            }

            const float xk = __int_as_float(
                __builtin_amdgcn_readlane(__float_as_int(x_cur), k));
            float acc0 = fmaf(xk, wi[0], bsum[0]);
            float acc1 = fmaf(xk, wi[1], bsum[1]);
            float acc2 = fmaf(xk, wi[2], bsum[2]);
            float acc3 = fmaf(xk, wi[3], bsum[3]);

            // ---- matvec: 130 v_dot2_f32_f16, weights resident in VGPRs ----
#pragma unroll
            for (int j = 0; j < NPAIR; ++j) {
                acc0 = dot2f(acc0, wp[0][j], hs[j]);
                acc1 = dot2f(acc1, wp[1][j], hs[j]);
                acc2 = dot2f(acc2, wp[2][j], hs[j]);
                acc3 = dot2f(acc3, wp[3][j], hs[j]);
                acc2 = dot2f(acc2, wlo2[j], hs[j]);   // g-gate lo correction
            }

            const float ig = fast_sigmoid(acc0);
            const float fg = fast_sigmoid(acc1);
            const float gg = fast_tanh(acc2);
            const float og = fast_sigmoid(acc3);
            c = fmaf(fg, c, ig * gg);
            h = og * fast_tanh(c);

            // defer output projection: 1 conflict-free ds_write per step
            sh[k * ROWP + L] = h;
        }

        __syncthreads();   // wave-sized block: compiles to a waitcnt fence

        // chunk-end projection (fp32): lane L handles step t0+L. Banks
        // (21L+kk)%32 -> exactly 2 lanes/bank (free, m136). W_lin is
        // lane-uniform -> scalar loads, amortized over 64 steps.
        float o0 = bl0, o1 = bl1;
        const float* hr = &sh[L * ROWP];
#pragma unroll
        for (int kk = 0; kk < H; ++kk) {
            const float hk = hr[kk];
            o0 = fmaf(hk, W_lin[kk],     o0);
            o1 = fmaf(hk, W_lin[H + kk], o1);
        }
        out0[t0 + L] = o0;            // coalesced, 64 steps at once
        out1[t0 + L] = o1;

        __syncthreads();   // reads done before next chunk's ds_writes
        x_cur = x_next;
    }
}

extern "C" void kernel_launch(void* const* d_in, const int* in_sizes, int n_in,
                              void* d_out, int out_size, void* d_ws, size_t ws_size,
                              hipStream_t stream) {
    const float* input = (const float*)d_in[0];
    const float* W_ih  = (const float*)d_in[1];
    const float* W_hh  = (const float*)d_in[2];
    const float* b_ih  = (const float*)d_in[3];
    const float* b_hh  = (const float*)d_in[4];
    const float* W_lin = (const float*)d_in[5];
    const float* b_lin = (const float*)d_in[6];
    float* outp = (float*)d_out;

    const int B = in_sizes[0] / T_LEN;   // 1024
    lstm_fused<<<dim3(B), dim3(64), 0, stream>>>(
        input, W_ih, W_hh, b_ih, b_hh, W_lin, b_lin, outp);
}